// Round 13
// baseline (461.201 us; speedup 1.0000x reference)
//
#include <hip/hip_runtime.h>
#include <hip/hip_bf16.h>

#define N_TOK 131072
#define DIM   512
#define HID   512
#define NEXP  10

using bf16x8 = __attribute__((ext_vector_type(8))) short;
using f32x4  = __attribute__((ext_vector_type(4))) float;

__device__ __forceinline__ short f2bf(float f) {
    union { float f; unsigned u; } v; v.f = f;
    unsigned u = v.u;
    return (short)((u + 0x7FFFu + ((u >> 16) & 1u)) >> 16);   // RNE
}

#define GLOAD16(g, l) __builtin_amdgcn_global_load_lds( \
    (const __attribute__((address_space(1))) void*)(g),  \
    (__attribute__((address_space(3))) void*)(l), 16, 0, 0)

// ---------------- router: logits = x @ Wr^T + br, argmax; also emits xb = bf16(x) ----------------
__global__ __launch_bounds__(256) void router_kernel(
    const float* __restrict__ x, const float* __restrict__ Wr,
    const float* __restrict__ br, int* __restrict__ eid,
    float* __restrict__ ids_out, int* __restrict__ counts,
    short* __restrict__ xb)
{
    __shared__ float wr[NEXP][DIM];
    __shared__ int lcnt[NEXP];
    int tid = threadIdx.x;
    for (int i = tid; i < NEXP * DIM / 4; i += 256)
        ((float4*)wr)[i] = ((const float4*)Wr)[i];
    if (tid < NEXP) lcnt[tid] = 0;
    __syncthreads();

    int lane  = tid & 63;
    int wave  = tid >> 6;
    int gwave = blockIdx.x * 4 + wave;
    int nwav  = gridDim.x * 4;

    for (int t = gwave; t < N_TOK; t += nwav) {
        const float4* xr = (const float4*)(x + (size_t)t * DIM);
        float4 v0 = xr[lane * 2], v1 = xr[lane * 2 + 1];
        float xf[8] = {v0.x, v0.y, v0.z, v0.w, v1.x, v1.y, v1.z, v1.w};
        bf16x8 p;
        #pragma unroll
        for (int j = 0; j < 8; ++j) p[j] = f2bf(xf[j]);
        *(bf16x8*)(xb + (size_t)t * DIM + lane * 8) = p;

        float dot[NEXP];
        #pragma unroll
        for (int e = 0; e < NEXP; ++e) {
            const float* wv = &wr[e][lane * 8];
            float s = 0.f;
            #pragma unroll
            for (int j = 0; j < 8; ++j) s = fmaf(xf[j], wv[j], s);
            dot[e] = s;
        }
        #pragma unroll
        for (int off = 32; off > 0; off >>= 1) {
            #pragma unroll
            for (int e = 0; e < NEXP; ++e) dot[e] += __shfl_xor(dot[e], off, 64);
        }
        if (lane == 0) {
            int best = 0; float bv = dot[0] + br[0];
            #pragma unroll
            for (int e = 1; e < NEXP; ++e) {
                float v = dot[e] + br[e];
                if (v > bv) { bv = v; best = e; }
            }
            eid[t] = best;
            ids_out[t] = (float)best;
            atomicAdd(&lcnt[best], 1);
        }
    }
    __syncthreads();
    if (tid < NEXP) atomicAdd(&counts[tid], lcnt[tid]);
}

// ---------------- prefix sums: token offsets + tile offsets (128-row tiles) ----------------
__global__ void offsets_kernel(const int* __restrict__ counts,
                               int* __restrict__ offsets, int* __restrict__ toff)
{
    if (threadIdx.x == 0) {
        int acc = 0, ta = 0;
        for (int e = 0; e < NEXP; ++e) {
            offsets[e] = acc; toff[e] = ta;
            acc += counts[e]; ta += (counts[e] + 127) >> 7;
        }
        offsets[NEXP] = acc; toff[NEXP] = ta;
    }
}

// ---------------- bucket scatter: perm[offset[e] + pos] = token ----------------
__global__ __launch_bounds__(256) void scatter_kernel(
    const int* __restrict__ eid, const int* __restrict__ offsets,
    int* __restrict__ cursors, int* __restrict__ perm)
{
    __shared__ int lcnt[NEXP], lbase[NEXP];
    int tid = threadIdx.x;
    if (tid < NEXP) lcnt[tid] = 0;
    __syncthreads();
    int t = blockIdx.x * 256 + tid;
    int e = 0, lpos = 0;
    if (t < N_TOK) {
        e = eid[t];
        lpos = atomicAdd(&lcnt[e], 1);
    }
    __syncthreads();
    if (tid < NEXP) lbase[tid] = atomicAdd(&cursors[tid], lcnt[tid]);
    __syncthreads();
    if (t < N_TOK) perm[offsets[e] + lbase[e] + lpos] = t;
}

// ---- transpose-convert weights: [512 k][512 n] f32 -> k-blocked bf16 [16][512 n][32 k] ----
__global__ __launch_bounds__(256) void wconvert_kernel(
    const float* __restrict__ W1, const float* __restrict__ W2,
    short* __restrict__ W1b, short* __restrict__ W2b)
{
    int mat = blockIdx.z;
    const float* src = (mat < NEXP) ? W1 + (size_t)mat * 512 * 512
                                    : W2 + (size_t)(mat - NEXP) * 512 * 512;
    short* dst = (mat < NEXP) ? W1b + (size_t)mat * 512 * 512
                              : W2b + (size_t)(mat - NEXP) * 512 * 512;
    __shared__ float tile[64][65];
    int r0 = blockIdx.y * 64, c0 = blockIdx.x * 64;   // r0 = k base, c0 = n base
    int tid = threadIdx.x;
    int tr = tid >> 4, tc4 = (tid & 15) * 4;
    #pragma unroll
    for (int i = 0; i < 4; ++i) {
        float4 v = *(const float4*)(src + (size_t)(r0 + i * 16 + tr) * 512 + c0 + tc4);
        tile[i * 16 + tr][tc4 + 0] = v.x; tile[i * 16 + tr][tc4 + 1] = v.y;
        tile[i * 16 + tr][tc4 + 2] = v.z; tile[i * 16 + tr][tc4 + 3] = v.w;
    }
    __syncthreads();
    int s   = (r0 + tc4) >> 5;     // 32k-block
    int kin = (r0 + tc4) & 31;
    #pragma unroll
    for (int i = 0; i < 4; ++i) {
        int cc = i * 16 + tr;      // n within tile
        ushort4 o;
        o.x = (ushort)f2bf(tile[tc4 + 0][cc]); o.y = (ushort)f2bf(tile[tc4 + 1][cc]);
        o.z = (ushort)f2bf(tile[tc4 + 2][cc]); o.w = (ushort)f2bf(tile[tc4 + 3][cc]);
        *(ushort4*)(dst + (size_t)s * 16384 + (size_t)(c0 + cc) * 32 + kin) = o;
    }
}

// ---------------- FUSED expert FFN: 128 rows/block, both layers, h never leaves LDS ----------------
// Phases: A: h0 = relu(xb.W1[:,0:256]+b1) -> Hb(64KB LDS)  [16 steps, A+B staged]
//         B1/B2: accP0/P1 += h0 . W2[0:256, 0:256 / 256:512]  [8 steps, B staged, A from Hb]
//         C: h1 -> Hb (overwrite)   D1/D2: += h1 . W2[256:512, *]
// Each phase = R11-proven 2-buffer / 2-barrier / counted-vmcnt ledger. LDS 113 KB -> 1 blk/CU.
// Staging swizzle q^((row>>1)&3) on Ab/Bb (R7-verified); Hb swizzle slot^(row&7) (512B rows).
__global__ __launch_bounds__(512, 2) void expert_fused(
    const short* __restrict__ xb, const short* __restrict__ W1b,
    const short* __restrict__ W2b, const float* __restrict__ b1,
    const float* __restrict__ b2,
    const int* __restrict__ offsets, const int* __restrict__ toff,
    const int* __restrict__ perm, float* __restrict__ out)
{
    int g = blockIdx.x;
    if (g >= toff[NEXP]) return;
    int e = 0;
    #pragma unroll
    for (int k = 1; k < NEXP; ++k) e += (g >= toff[k]);
    int beg = offsets[e], cnt = offsets[e + 1] - beg;
    int m0 = (g - toff[e]) * 128;

    // LDS map: Ab dbuf [0,16K) ; Bb dbuf [16K,48K) ; Hb [48K,112K) ; toks @112K
    __shared__ char SMEM[114688 + 512];
    #define ABOF(b) ((b) * 8192)
    #define BBOF(b) (16384 + (b) * 16384)
    #define HOFF    49152

    int tid = threadIdx.x, lane = tid & 63, w = tid >> 6;
    int* toks = (int*)(SMEM + 114688);
    if (tid < 128) toks[tid] = perm[beg + min(m0 + tid, cnt - 1)];
    __syncthreads();

    const short* W1e = W1b + (size_t)e * 512 * 512;
    const short* W2e = W2b + (size_t)e * 512 * 512;
    int srow = tid >> 2;                   // 0..127
    int kqp  = tid & 3;
    int ql   = kqp ^ ((srow >> 1) & 3);    // logical k-quarter at this linear slot
    const short* aS = xb + (size_t)toks[srow] * DIM + ql * 8;

    // fragment read offsets (staging bufs, swizzled)
    int wr = w >> 2, wc = w & 3, lrow = lane & 15, kq = lane >> 4;
    int offA[4], offB[4], hbase[4], hxor[4];
    #pragma unroll
    for (int i = 0; i < 4; ++i) {
        int r = wr * 64 + i * 16 + lrow;
        offA[i]  = r * 64 + (kq ^ ((r >> 1) & 3)) * 16;
        hbase[i] = HOFF + r * 512;
        hxor[i]  = r & 7;
    }
    #pragma unroll
    for (int j = 0; j < 4; ++j) {
        int r = wc * 64 + j * 16 + lrow;
        offB[j] = r * 64 + (kq ^ ((r >> 1) & 3)) * 16;
    }

    f32x4 accL[4][4], accP0[4][4], accP1[4][4];
    #pragma unroll
    for (int i = 0; i < 4; ++i)
        #pragma unroll
        for (int j = 0; j < 4; ++j) {
            accP0[i][j] = (f32x4){0.f, 0.f, 0.f, 0.f};
            accP1[i][j] = (f32x4){0.f, 0.f, 0.f, 0.f};
        }

    // ---- phase A/C: layer-1 over one 256-col half; writes h into Hb ----
    auto phaseAC = [&](int nb) {
        #pragma unroll
        for (int i = 0; i < 4; ++i)
            #pragma unroll
            for (int j = 0; j < 4; ++j) accL[i][j] = (f32x4){0.f, 0.f, 0.f, 0.f};

        auto stage = [&](int t, int b) {
            const short* bs = W1e + (size_t)t * 16384 + (size_t)(nb + srow) * 32 + ql * 8;
            GLOAD16(bs,        SMEM + BBOF(b) + tid * 16);
            GLOAD16(bs + 4096, SMEM + BBOF(b) + 8192 + tid * 16);
            GLOAD16(aS + t * 32, SMEM + ABOF(b) + tid * 16);
        };
        auto comp = [&](int b) {
            bf16x8 af[4], bv[4];
            #pragma unroll
            for (int i = 0; i < 4; ++i) af[i] = *(const bf16x8*)(SMEM + ABOF(b) + offA[i]);
            #pragma unroll
            for (int j = 0; j < 4; ++j) bv[j] = *(const bf16x8*)(SMEM + BBOF(b) + offB[j]);
            __builtin_amdgcn_s_setprio(1);
            #pragma unroll
            for (int i = 0; i < 4; ++i)
                #pragma unroll
                for (int j = 0; j < 4; ++j)
                    accL[i][j] = __builtin_amdgcn_mfma_f32_16x16x32_bf16(af[i], bv[j], accL[i][j], 0, 0, 0);
            __builtin_amdgcn_s_setprio(0);
        };

        stage(0, 0); stage(1, 1);
        asm volatile("s_waitcnt vmcnt(3)" ::: "memory");
        __builtin_amdgcn_s_barrier();
        #pragma unroll
        for (int t = 0; t < 16; ++t) {
            comp(t & 1);
            if (t == 15) break;
            __builtin_amdgcn_s_barrier();
            if (t + 2 < 16) {
                stage(t + 2, t & 1);
                asm volatile("s_waitcnt vmcnt(3)" ::: "memory");
            } else {
                asm volatile("s_waitcnt vmcnt(0)" ::: "memory");
            }
            __builtin_amdgcn_s_barrier();
        }
        // epilogue: bias + relu -> Hb (swizzled: slot' = (col>>3) ^ (row&7))
        const float* b1e = b1 + (size_t)e * 512 + nb;
        float bvv[4];
        #pragma unroll
        for (int j = 0; j < 4; ++j) bvv[j] = b1e[wc * 64 + j * 16 + lrow];
        #pragma unroll
        for (int i = 0; i < 4; ++i)
            #pragma unroll
            for (int q = 0; q < 4; ++q) {
                int row = wr * 64 + i * 16 + kq * 4 + q;
                #pragma unroll
                for (int j = 0; j < 4; ++j) {
                    int col = wc * 64 + j * 16 + lrow;
                    float v = accL[i][j][q] + bvv[j];
                    v = v > 0.f ? v : 0.f;
                    int slot = (col >> 3) ^ (row & 7);
                    *(short*)(SMEM + HOFF + row * 512 + slot * 16 + (col & 7) * 2) = f2bf(v);
                }
            }
        __syncthreads();
    };

    // ---- phase B/D: layer-2 k-half; A from Hb, B staged; accumulates into acc ----
    auto phaseBD = [&](int ktbase, int nb2, f32x4 (&acc)[4][4]) {
        auto stage = [&](int kt, int b) {
            const short* bs = W2e + (size_t)kt * 16384 + (size_t)(nb2 + srow) * 32 + ql * 8;
            GLOAD16(bs,        SMEM + BBOF(b) + tid * 16);
            GLOAD16(bs + 4096, SMEM + BBOF(b) + 8192 + tid * 16);
        };
        auto comp = [&](int b, int t) {
            bf16x8 af[4], bv[4];
            #pragma unroll
            for (int i = 0; i < 4; ++i)
                af[i] = *(const bf16x8*)(SMEM + hbase[i] + (((t * 4 + kq) ^ hxor[i]) << 4));
            #pragma unroll
            for (int j = 0; j < 4; ++j) bv[j] = *(const bf16x8*)(SMEM + BBOF(b) + offB[j]);
            __builtin_amdgcn_s_setprio(1);
            #pragma unroll
            for (int i = 0; i < 4; ++i)
                #pragma unroll
                for (int j = 0; j < 4; ++j)
                    acc[i][j] = __builtin_amdgcn_mfma_f32_16x16x32_bf16(af[i], bv[j], acc[i][j], 0, 0, 0);
            __builtin_amdgcn_s_setprio(0);
        };

        stage(ktbase + 0, 0); stage(ktbase + 1, 1);
        asm volatile("s_waitcnt vmcnt(2)" ::: "memory");
        __builtin_amdgcn_s_barrier();
        #pragma unroll
        for (int t = 0; t < 8; ++t) {
            comp(t & 1, t);
            if (t == 7) break;
            __builtin_amdgcn_s_barrier();
            if (t + 2 < 8) {
                stage(ktbase + t + 2, t & 1);
                asm volatile("s_waitcnt vmcnt(2)" ::: "memory");
            } else {
                asm volatile("s_waitcnt vmcnt(0)" ::: "memory");
            }
            __builtin_amdgcn_s_barrier();
        }
        __syncthreads();   // all comps done before next phase restages / rewrites Hb
    };

    phaseAC(0);                 // h0 -> Hb
    phaseBD(0, 0,   accP0);     // out[:,  0:256] += h0 . W2[0:256,   0:256]
    phaseBD(0, 256, accP1);     // out[:,256:512] += h0 . W2[0:256, 256:512]
    phaseAC(256);               // h1 -> Hb
    phaseBD(8, 0,   accP0);     // += h1 . W2[256:512,   0:256]
    phaseBD(8, 256, accP1);     // += h1 . W2[256:512, 256:512]

    // ---- final epilogue: bias + f32 scatter stores ----
    const float* b2e = b2 + (size_t)e * 512;
    #pragma unroll
    for (int i = 0; i < 4; ++i) {
        #pragma unroll
        for (int q = 0; q < 4; ++q) {
            int rr = wr * 64 + i * 16 + kq * 4 + q;
            if (m0 + rr < cnt) {
                float* op = out + (size_t)toks[rr] * HID;
                int c0 = wc * 64 + lrow;
                #pragma unroll
                for (int j = 0; j < 4; ++j) {
                    op[c0 + j * 16]       = accP0[i][j][q] + b2e[c0 + j * 16];
                    op[256 + c0 + j * 16] = accP1[i][j][q] + b2e[256 + c0 + j * 16];
                }
            }
        }
    }
    #undef ABOF
    #undef BBOF
    #undef HOFF
}

extern "C" void kernel_launch(void* const* d_in, const int* in_sizes, int n_in,
                              void* d_out, int out_size, void* d_ws, size_t ws_size,
                              hipStream_t stream)
{
    const float* x  = (const float*)d_in[0];
    const float* Wr = (const float*)d_in[1];
    const float* br = (const float*)d_in[2];
    const float* W1 = (const float*)d_in[3];
    const float* b1 = (const float*)d_in[4];
    const float* W2 = (const float*)d_in[5];
    const float* b2 = (const float*)d_in[6];

    float* out     = (float*)d_out;
    float* ids_out = out + (size_t)N_TOK * HID;

    char* ws     = (char*)d_ws;
    int* counts  = (int*)ws;            // 16 ints
    int* offsets = counts + 16;         // 11 used
    int* toff    = counts + 32;         // 11 used
    int* cursors = counts + 48;         // 16
    int* eid     = (int*)(ws + 1024);
    int* perm    = eid + N_TOK;
    short* W1b   = (short*)(ws + 1024 + (size_t)2 * N_TOK * 4);
    short* W2b   = W1b + (size_t)NEXP * 512 * 512;
    short* xb    = W2b + (size_t)NEXP * 512 * 512;

    hipMemsetAsync(d_ws, 0, 1024, stream);
    router_kernel<<<2048, 256, 0, stream>>>(x, Wr, br, eid, ids_out, counts, xb);
    wconvert_kernel<<<dim3(8, 8, 2 * NEXP), 256, 0, stream>>>(W1, W2, W1b, W2b);
    offsets_kernel<<<1, 64, 0, stream>>>(counts, offsets, toff);
    scatter_kernel<<<512, 256, 0, stream>>>(eid, offsets, cursors, perm);

    int ntiles = (N_TOK + 127) / 128 + NEXP;   // upper bound on 128-row tiles
    expert_fused<<<ntiles, 512, 0, stream>>>(xb, W1b, W2b, b1, b2,
                                             offsets, toff, perm, out);
}

// Round 14
// 365.465 us; speedup vs baseline: 1.2620x; 1.2620x over previous
//
#include <hip/hip_runtime.h>
#include <hip/hip_bf16.h>

#define N_TOK 131072
#define DIM   512
#define HID   512
#define NEXP  10

using bf16x8 = __attribute__((ext_vector_type(8))) short;
using f32x4  = __attribute__((ext_vector_type(4))) float;

__device__ __forceinline__ short f2bf(float f) {
    union { float f; unsigned u; } v; v.f = f;
    unsigned u = v.u;
    return (short)((u + 0x7FFFu + ((u >> 16) & 1u)) >> 16);   // RNE
}

#define GLOAD16(g, l) __builtin_amdgcn_global_load_lds( \
    (const __attribute__((address_space(1))) void*)(g),  \
    (__attribute__((address_space(3))) void*)(l), 16, 0, 0)

// ---------------- router: logits = x @ Wr^T + br, argmax; also emits xb = bf16(x) ----------------
__global__ __launch_bounds__(256) void router_kernel(
    const float* __restrict__ x, const float* __restrict__ Wr,
    const float* __restrict__ br, int* __restrict__ eid,
    float* __restrict__ ids_out, int* __restrict__ counts,
    short* __restrict__ xb)
{
    __shared__ float wr[NEXP][DIM];
    __shared__ int lcnt[NEXP];
    int tid = threadIdx.x;
    for (int i = tid; i < NEXP * DIM / 4; i += 256)
        ((float4*)wr)[i] = ((const float4*)Wr)[i];
    if (tid < NEXP) lcnt[tid] = 0;
    __syncthreads();

    int lane  = tid & 63;
    int wave  = tid >> 6;
    int gwave = blockIdx.x * 4 + wave;
    int nwav  = gridDim.x * 4;

    for (int t = gwave; t < N_TOK; t += nwav) {
        const float4* xr = (const float4*)(x + (size_t)t * DIM);
        float4 v0 = xr[lane * 2], v1 = xr[lane * 2 + 1];
        float xf[8] = {v0.x, v0.y, v0.z, v0.w, v1.x, v1.y, v1.z, v1.w};
        bf16x8 p;
        #pragma unroll
        for (int j = 0; j < 8; ++j) p[j] = f2bf(xf[j]);
        *(bf16x8*)(xb + (size_t)t * DIM + lane * 8) = p;

        float dot[NEXP];
        #pragma unroll
        for (int e = 0; e < NEXP; ++e) {
            const float* wv = &wr[e][lane * 8];
            float s = 0.f;
            #pragma unroll
            for (int j = 0; j < 8; ++j) s = fmaf(xf[j], wv[j], s);
            dot[e] = s;
        }
        #pragma unroll
        for (int off = 32; off > 0; off >>= 1) {
            #pragma unroll
            for (int e = 0; e < NEXP; ++e) dot[e] += __shfl_xor(dot[e], off, 64);
        }
        if (lane == 0) {
            int best = 0; float bv = dot[0] + br[0];
            #pragma unroll
            for (int e = 1; e < NEXP; ++e) {
                float v = dot[e] + br[e];
                if (v > bv) { bv = v; best = e; }
            }
            eid[t] = best;
            ids_out[t] = (float)best;
            atomicAdd(&lcnt[best], 1);
        }
    }
    __syncthreads();
    if (tid < NEXP) atomicAdd(&counts[tid], lcnt[tid]);
}

// ---------------- prefix sums: token offsets + tile offsets (256-row tiles) ----------------
__global__ void offsets_kernel(const int* __restrict__ counts,
                               int* __restrict__ offsets, int* __restrict__ toff)
{
    if (threadIdx.x == 0) {
        int acc = 0, ta = 0;
        for (int e = 0; e < NEXP; ++e) {
            offsets[e] = acc; toff[e] = ta;
            acc += counts[e]; ta += (counts[e] + 255) >> 8;
        }
        offsets[NEXP] = acc; toff[NEXP] = ta;
    }
}

// ---------------- bucket scatter: perm[offset[e] + pos] = token ----------------
__global__ __launch_bounds__(256) void scatter_kernel(
    const int* __restrict__ eid, const int* __restrict__ offsets,
    int* __restrict__ cursors, int* __restrict__ perm)
{
    __shared__ int lcnt[NEXP], lbase[NEXP];
    int tid = threadIdx.x;
    if (tid < NEXP) lcnt[tid] = 0;
    __syncthreads();
    int t = blockIdx.x * 256 + tid;
    int e = 0, lpos = 0;
    if (t < N_TOK) {
        e = eid[t];
        lpos = atomicAdd(&lcnt[e], 1);
    }
    __syncthreads();
    if (tid < NEXP) lbase[tid] = atomicAdd(&cursors[tid], lcnt[tid]);
    __syncthreads();
    if (t < N_TOK) perm[offsets[e] + lbase[e] + lpos] = t;
}

// ---- transpose-convert weights: [512 k][512 n] f32 -> k-blocked bf16 [16][512 n][32 k] ----
__global__ __launch_bounds__(256) void wconvert_kernel(
    const float* __restrict__ W1, const float* __restrict__ W2,
    short* __restrict__ W1b, short* __restrict__ W2b)
{
    int mat = blockIdx.z;
    const float* src = (mat < NEXP) ? W1 + (size_t)mat * 512 * 512
                                    : W2 + (size_t)(mat - NEXP) * 512 * 512;
    short* dst = (mat < NEXP) ? W1b + (size_t)mat * 512 * 512
                              : W2b + (size_t)(mat - NEXP) * 512 * 512;
    __shared__ float tile[64][65];
    int r0 = blockIdx.y * 64, c0 = blockIdx.x * 64;   // r0 = k base, c0 = n base
    int tid = threadIdx.x;
    int tr = tid >> 4, tc4 = (tid & 15) * 4;
    #pragma unroll
    for (int i = 0; i < 4; ++i) {
        float4 v = *(const float4*)(src + (size_t)(r0 + i * 16 + tr) * 512 + c0 + tc4);
        tile[i * 16 + tr][tc4 + 0] = v.x; tile[i * 16 + tr][tc4 + 1] = v.y;
        tile[i * 16 + tr][tc4 + 2] = v.z; tile[i * 16 + tr][tc4 + 3] = v.w;
    }
    __syncthreads();
    int s   = (r0 + tc4) >> 5;     // 32k-block
    int kin = (r0 + tc4) & 31;
    #pragma unroll
    for (int i = 0; i < 4; ++i) {
        int cc = i * 16 + tr;      // n within tile
        ushort4 o;
        o.x = (ushort)f2bf(tile[tc4 + 0][cc]); o.y = (ushort)f2bf(tile[tc4 + 1][cc]);
        o.z = (ushort)f2bf(tile[tc4 + 2][cc]); o.w = (ushort)f2bf(tile[tc4 + 3][cc]);
        *(ushort4*)(dst + (size_t)s * 16384 + (size_t)(c0 + cc) * 32 + kin) = o;
    }
}

// ------- MFMA expert GEMM, 8-phase template (T3+T4): 256 x 256, BK=64, 8 waves, 128 KB LDS -------
// K=512 -> 8 K-tiles x 4 phases (kh = k-half of 64, rh = row-half of wave's 128 rows).
// Per phase: ds_read frags -> stage one 16KB k-split half of tile t+1 -> counted vmcnt at kh
// boundaries -> barrier -> lgkmcnt(0) -> sched_barrier(0) -> setprio(1) -> 16 MFMA -> setprio(0)
// -> barrier. Ledger: every half issued 4 phases before use; waits leave 4 loads in flight
// (vmcnt(0) only in tile-7 tail).
// LDS 16B-slot swizzle q^((row>>1)&3) (R7-verified) on A and B, source-side + read-side.
// LAYER==1: A = gathered xb rows, out = relu(.+b1) -> h   LAYER==2: A = h, out = .+b2 -> out[tok]
template<int LAYER>
__global__ __launch_bounds__(512, 2) void expert_gemm(
    const short* __restrict__ xb, const short* __restrict__ hA,
    const short* __restrict__ WT, const float* __restrict__ bias,
    const int* __restrict__ offsets, const int* __restrict__ toff,
    const int* __restrict__ perm,
    short* __restrict__ hOut, float* __restrict__ out)
{
    int g = blockIdx.x;
    if (g >= toff[NEXP]) return;
    int e = 0;
    #pragma unroll
    for (int k = 1; k < NEXP; ++k) e += (g >= toff[k]);
    int beg = offsets[e], cnt = offsets[e + 1] - beg;
    int m0 = (g - toff[e]) * 256;
    int nb = blockIdx.y * 256;

    // LDS: A bufs [0,64K): b*32768 + kh*16384 ; B bufs [64K,128K): 65536 + b*32768 + kh*16384
    __shared__ char SMEM[132096];
    int* toks = (int*)(SMEM + 131072);

    int tid = threadIdx.x, lane = tid & 63, w = tid >> 6;
    if (tid < 256) toks[tid] = perm[beg + min(m0 + tid, cnt - 1)];
    __syncthreads();

    const short* WTe = WT + (size_t)e * 512 * 512;
    int srow = tid >> 2;                   // 0..127
    int kqp  = tid & 3;
    int ql   = kqp ^ ((srow >> 1) & 3);    // logical k-quarter at this linear slot
    const short *aS0, *aS1;
    if (LAYER == 1) {
        aS0 = xb + (size_t)toks[srow] * DIM + ql * 8;
        aS1 = xb + (size_t)toks[srow + 128] * DIM + ql * 8;
    } else {
        aS0 = hA + (size_t)(beg + min(m0 + srow, cnt - 1)) * HID + ql * 8;
        aS1 = hA + (size_t)(beg + min(m0 + srow + 128, cnt - 1)) * HID + ql * 8;
    }
    const short* bS = WTe + (size_t)(nb + srow) * 32 + ql * 8;   // + (t*2+kh)*16384; col+128 -> +4096

    // ---- fragment read offsets (swizzled, bytes within a 16KB k-half) ----
    int wr = w >> 2, wc = w & 3, lrow = lane & 15, kq = lane >> 4;
    int offA[8], offB[4];
    #pragma unroll
    for (int f = 0; f < 8; ++f) {
        int r = wr * 128 + f * 16 + lrow;
        offA[f] = r * 64 + ((kq ^ ((r >> 1) & 3)) << 4);
    }
    #pragma unroll
    for (int j = 0; j < 4; ++j) {
        int c = wc * 64 + j * 16 + lrow;
        offB[j] = c * 64 + ((kq ^ ((c >> 1) & 3)) << 4);
    }

    f32x4 acc[8][4];
    #pragma unroll
    for (int f = 0; f < 8; ++f)
        #pragma unroll
        for (int j = 0; j < 4; ++j) acc[f][j] = (f32x4){0.f, 0.f, 0.f, 0.f};

    // stage half p of K-tile t into buffer b: p0=A-k0, p1=B-k0, p2=A-k1, p3=B-k1 (2 GLOAD16)
    auto stage_half = [&](int t, int p, int b) {
        int kh = p >> 1;
        if ((p & 1) == 0) {
            GLOAD16(aS0 + t * 64 + kh * 32, SMEM + b * 32768 + kh * 16384 + tid * 16);
            GLOAD16(aS1 + t * 64 + kh * 32, SMEM + b * 32768 + kh * 16384 + 8192 + tid * 16);
        } else {
            const short* s = bS + (size_t)(t * 2 + kh) * 16384;
            GLOAD16(s,        SMEM + 65536 + b * 32768 + kh * 16384 + tid * 16);
            GLOAD16(s + 4096, SMEM + 65536 + b * 32768 + kh * 16384 + 8192 + tid * 16);
        }
    };

    // ---- prologue: all 4 halves of tile 0 into buf 0; wait k0 halves (k1 stays in flight) ----
    stage_half(0, 0, 0); stage_half(0, 1, 0); stage_half(0, 2, 0); stage_half(0, 3, 0);
    asm volatile("s_waitcnt vmcnt(4)" ::: "memory");
    __builtin_amdgcn_s_barrier();

    bf16x8 bv[4];
    #pragma unroll
    for (int t = 0; t < 8; ++t) {
        int b = t & 1;
        #pragma unroll
        for (int p = 0; p < 4; ++p) {
            int kh = p >> 1, rh = p & 1;
            const char* ABp = SMEM + b * 32768 + kh * 16384;
            const char* BBp = SMEM + 65536 + b * 32768 + kh * 16384;
            bf16x8 af[4];
            if (rh == 0) {
                #pragma unroll
                for (int j = 0; j < 4; ++j) bv[j] = *(const bf16x8*)(BBp + offB[j]);
            }
            #pragma unroll
            for (int i = 0; i < 4; ++i) af[i] = *(const bf16x8*)(ABp + offA[rh * 4 + i]);

            if (t < 7) stage_half(t + 1, p, b ^ 1);

            if (p == 1) {
                if (t < 7) asm volatile("s_waitcnt vmcnt(4)" ::: "memory");
                else       asm volatile("s_waitcnt vmcnt(0)" ::: "memory");
            } else if (p == 3 && t < 7) {
                asm volatile("s_waitcnt vmcnt(4)" ::: "memory");
            }
            __builtin_amdgcn_s_barrier();
            asm volatile("s_waitcnt lgkmcnt(0)" ::: "memory");
            __builtin_amdgcn_sched_barrier(0);
            __builtin_amdgcn_s_setprio(1);
            #pragma unroll
            for (int i = 0; i < 4; ++i)
                #pragma unroll
                for (int j = 0; j < 4; ++j)
                    acc[rh * 4 + i][j] = __builtin_amdgcn_mfma_f32_16x16x32_bf16(
                        af[i], bv[j], acc[rh * 4 + i][j], 0, 0, 0);
            __builtin_amdgcn_s_setprio(0);
            if (!(t == 7 && p == 3)) __builtin_amdgcn_s_barrier();
        }
    }

    // ---- epilogue ----
    const float* be = bias + (size_t)e * 512;
    int colb = nb + wc * 64 + lrow;
    float bvv[4];
    #pragma unroll
    for (int j = 0; j < 4; ++j) bvv[j] = be[colb + j * 16];

    #pragma unroll
    for (int f = 0; f < 8; ++f) {
        #pragma unroll
        for (int q = 0; q < 4; ++q) {
            int rr = wr * 128 + f * 16 + kq * 4 + q;
            if (m0 + rr < cnt) {
                if (LAYER == 1) {
                    short* hp = hOut + (size_t)(beg + m0 + rr) * HID + colb;
                    #pragma unroll
                    for (int j = 0; j < 4; ++j) {
                        float v = acc[f][j][q] + bvv[j];
                        hp[j * 16] = f2bf(v > 0.f ? v : 0.f);
                    }
                } else {
                    float* op = out + (size_t)toks[rr] * HID + colb;
                    #pragma unroll
                    for (int j = 0; j < 4; ++j)
                        op[j * 16] = acc[f][j][q] + bvv[j];
                }
            }
        }
    }
}

extern "C" void kernel_launch(void* const* d_in, const int* in_sizes, int n_in,
                              void* d_out, int out_size, void* d_ws, size_t ws_size,
                              hipStream_t stream)
{
    const float* x  = (const float*)d_in[0];
    const float* Wr = (const float*)d_in[1];
    const float* br = (const float*)d_in[2];
    const float* W1 = (const float*)d_in[3];
    const float* b1 = (const float*)d_in[4];
    const float* W2 = (const float*)d_in[5];
    const float* b2 = (const float*)d_in[6];

    float* out     = (float*)d_out;
    float* ids_out = out + (size_t)N_TOK * HID;

    char* ws     = (char*)d_ws;
    int* counts  = (int*)ws;            // 16 ints
    int* offsets = counts + 16;         // 11 used
    int* toff    = counts + 32;         // 11 used
    int* cursors = counts + 48;         // 16
    int* eid     = (int*)(ws + 1024);
    int* perm    = eid + N_TOK;
    short* W1b   = (short*)(ws + 1024 + (size_t)2 * N_TOK * 4);
    short* W2b   = W1b + (size_t)NEXP * 512 * 512;
    short* h     = W2b + (size_t)NEXP * 512 * 512;
    short* xb    = h   + (size_t)N_TOK * HID;

    hipMemsetAsync(d_ws, 0, 1024, stream);
    router_kernel<<<2048, 256, 0, stream>>>(x, Wr, br, eid, ids_out, counts, xb);
    wconvert_kernel<<<dim3(8, 8, 2 * NEXP), 256, 0, stream>>>(W1, W2, W1b, W2b);
    offsets_kernel<<<1, 64, 0, stream>>>(counts, offsets, toff);
    scatter_kernel<<<512, 256, 0, stream>>>(eid, offsets, cursors, perm);

    int ntiles = (N_TOK + 255) / 256 + NEXP;   // upper bound on 256-row tiles
    expert_gemm<1><<<dim3(ntiles, 2), 512, 0, stream>>>(xb, nullptr, W1b, b1, offsets, toff, perm, h, nullptr);
    expert_gemm<2><<<dim3(ntiles, 2), 512, 0, stream>>>(nullptr, h, W2b, b2, offsets, toff, perm, nullptr, out);
}

// Round 17
// 359.055 us; speedup vs baseline: 1.2845x; 1.0179x over previous
//
#include <hip/hip_runtime.h>
#include <hip/hip_bf16.h>

#define N_TOK 131072
#define DIM   512
#define HID   512
#define NEXP  10

using bf16x8 = __attribute__((ext_vector_type(8))) short;
using f32x4  = __attribute__((ext_vector_type(4))) float;

__device__ __forceinline__ short f2bf(float f) {
    union { float f; unsigned u; } v; v.f = f;
    unsigned u = v.u;
    return (short)((u + 0x7FFFu + ((u >> 16) & 1u)) >> 16);   // RNE
}

#define GLOAD16(g, l) __builtin_amdgcn_global_load_lds( \
    (const __attribute__((address_space(1))) void*)(g),  \
    (__attribute__((address_space(3))) void*)(l), 16, 0, 0)

// ---------------- router: logits = x @ Wr^T + br, argmax; also emits xb = bf16(x) ----------------
__global__ __launch_bounds__(256) void router_kernel(
    const float* __restrict__ x, const float* __restrict__ Wr,
    const float* __restrict__ br, int* __restrict__ eid,
    float* __restrict__ ids_out, int* __restrict__ counts,
    short* __restrict__ xb)
{
    __shared__ float wr[NEXP][DIM];
    __shared__ int lcnt[NEXP];
    int tid = threadIdx.x;
    for (int i = tid; i < NEXP * DIM / 4; i += 256)
        ((float4*)wr)[i] = ((const float4*)Wr)[i];
    if (tid < NEXP) lcnt[tid] = 0;
    __syncthreads();

    int lane  = tid & 63;
    int wave  = tid >> 6;
    int gwave = blockIdx.x * 4 + wave;
    int nwav  = gridDim.x * 4;

    for (int t = gwave; t < N_TOK; t += nwav) {
        const float4* xr = (const float4*)(x + (size_t)t * DIM);
        float4 v0 = xr[lane * 2], v1 = xr[lane * 2 + 1];
        float xf[8] = {v0.x, v0.y, v0.z, v0.w, v1.x, v1.y, v1.z, v1.w};
        bf16x8 p;
        #pragma unroll
        for (int j = 0; j < 8; ++j) p[j] = f2bf(xf[j]);
        *(bf16x8*)(xb + (size_t)t * DIM + lane * 8) = p;

        float dot[NEXP];
        #pragma unroll
        for (int e = 0; e < NEXP; ++e) {
            const float* wv = &wr[e][lane * 8];
            float s = 0.f;
            #pragma unroll
            for (int j = 0; j < 8; ++j) s = fmaf(xf[j], wv[j], s);
            dot[e] = s;
        }
        #pragma unroll
        for (int off = 32; off > 0; off >>= 1) {
            #pragma unroll
            for (int e = 0; e < NEXP; ++e) dot[e] += __shfl_xor(dot[e], off, 64);
        }
        if (lane == 0) {
            int best = 0; float bv = dot[0] + br[0];
            #pragma unroll
            for (int e = 1; e < NEXP; ++e) {
                float v = dot[e] + br[e];
                if (v > bv) { bv = v; best = e; }
            }
            eid[t] = best;
            ids_out[t] = (float)best;
            atomicAdd(&lcnt[best], 1);
        }
    }
    __syncthreads();
    if (tid < NEXP) atomicAdd(&counts[tid], lcnt[tid]);
}

// ---------------- prefix sums: token offsets + tile offsets (64-row tiles) ----------------
__global__ void offsets_kernel(const int* __restrict__ counts,
                               int* __restrict__ offsets, int* __restrict__ toff)
{
    if (threadIdx.x == 0) {
        int acc = 0, ta = 0;
        for (int e = 0; e < NEXP; ++e) {
            offsets[e] = acc; toff[e] = ta;
            acc += counts[e]; ta += (counts[e] + 63) >> 6;
        }
        offsets[NEXP] = acc; toff[NEXP] = ta;
    }
}

// ---------------- bucket scatter: perm[offset[e] + pos] = token ----------------
__global__ __launch_bounds__(256) void scatter_kernel(
    const int* __restrict__ eid, const int* __restrict__ offsets,
    int* __restrict__ cursors, int* __restrict__ perm)
{
    __shared__ int lcnt[NEXP], lbase[NEXP];
    int tid = threadIdx.x;
    if (tid < NEXP) lcnt[tid] = 0;
    __syncthreads();
    int t = blockIdx.x * 256 + tid;
    int e = 0, lpos = 0;
    if (t < N_TOK) {
        e = eid[t];
        lpos = atomicAdd(&lcnt[e], 1);
    }
    __syncthreads();
    if (tid < NEXP) lbase[tid] = atomicAdd(&cursors[tid], lcnt[tid]);
    __syncthreads();
    if (t < N_TOK) perm[offsets[e] + lbase[e] + lpos] = t;
}

// ---- transpose-convert weights: [512 k][512 n] f32 -> k-blocked bf16 [16][512 n][32 k] ----
__global__ __launch_bounds__(256) void wconvert_kernel(
    const float* __restrict__ W1, const float* __restrict__ W2,
    short* __restrict__ W1b, short* __restrict__ W2b)
{
    int mat = blockIdx.z;
    const float* src = (mat < NEXP) ? W1 + (size_t)mat * 512 * 512
                                    : W2 + (size_t)(mat - NEXP) * 512 * 512;
    short* dst = (mat < NEXP) ? W1b + (size_t)mat * 512 * 512
                              : W2b + (size_t)(mat - NEXP) * 512 * 512;
    __shared__ float tile[64][65];
    int r0 = blockIdx.y * 64, c0 = blockIdx.x * 64;   // r0 = k base, c0 = n base
    int tid = threadIdx.x;
    int tr = tid >> 4, tc4 = (tid & 15) * 4;
    #pragma unroll
    for (int i = 0; i < 4; ++i) {
        float4 v = *(const float4*)(src + (size_t)(r0 + i * 16 + tr) * 512 + c0 + tc4);
        tile[i * 16 + tr][tc4 + 0] = v.x; tile[i * 16 + tr][tc4 + 1] = v.y;
        tile[i * 16 + tr][tc4 + 2] = v.z; tile[i * 16 + tr][tc4 + 3] = v.w;
    }
    __syncthreads();
    int s   = (r0 + tc4) >> 5;     // 32k-block
    int kin = (r0 + tc4) & 31;
    #pragma unroll
    for (int i = 0; i < 4; ++i) {
        int cc = i * 16 + tr;      // n within tile
        ushort4 o;
        o.x = (ushort)f2bf(tile[tc4 + 0][cc]); o.y = (ushort)f2bf(tile[tc4 + 1][cc]);
        o.z = (ushort)f2bf(tile[tc4 + 2][cc]); o.w = (ushort)f2bf(tile[tc4 + 3][cc]);
        *(ushort4*)(dst + (size_t)s * 16384 + (size_t)(c0 + cc) * 32 + kin) = o;
    }
}

// ---------------- FUSED expert FFN v2: 64 rows x 512 cols per block, one reused acc ----------------
// L1 (16 steps): h = relu(xb[toks] . W1 + b1) -> Hb (64 KB LDS, slot^(row&7) swizzle, 1KB rows)
// L2 (16 steps): out = Hb . W2 + b2 -> f32 scatter. A-frags from Hb (no staging).
// Ledger (R11 2-buffer counted-vmcnt):
//   L1 issues/step: even t = 5 (B(t+2) 4 + A-pair(t/2+1) 1), odd t = 4 (B only).
//   Waits: even t -> vmcnt(5), odd t -> vmcnt(4), t=14 -> vmcnt(0).
//   L2: 4 loads/step, vmcnt(4), tail vmcnt(0).
// Swizzles: A-pair buf slot8 ^ (row&7); B 16B-slot q ^ ((col>>1)&3) (R7-verified conflicts->0);
//           Hb slot64 ^ (row&7). All applied source-side (linear gload dest) + read-side.
// VGPR budget: acc[2][8] f32x4 = 64 (REUSED across layers), bv 32, af 8, addr ~30 -> ~145, no spill.
__global__ __launch_bounds__(512, 2) void expert_fused(
    const short* __restrict__ xb, const short* __restrict__ W1,
    const short* __restrict__ W2, const float* __restrict__ b1,
    const float* __restrict__ b2,
    const int* __restrict__ offsets, const int* __restrict__ toff,
    const int* __restrict__ perm, float* __restrict__ out)
{
    // bijective XCD swizzle (m204): contiguous tile chunks per XCD -> per-XCD L2 holds ~1.3 experts' W
    int nwg = gridDim.x, orig = blockIdx.x;
    int q8 = nwg >> 3, r8 = nwg & 7, xcd = orig & 7;
    int g = (xcd < r8 ? xcd * (q8 + 1) : r8 * (q8 + 1) + (xcd - r8) * q8) + (orig >> 3);
    if (g >= toff[NEXP]) return;
    int e = 0;
    #pragma unroll
    for (int k = 1; k < NEXP; ++k) e += (g >= toff[k]);
    int beg = offsets[e], cnt = offsets[e + 1] - beg;
    int m0 = (g - toff[e]) * 64;

    // LDS: A pair-bufs [0,16K) ; B dbuf [16K,80K) ; Hb [80K,144K) ; toks @144K
    __shared__ char SMEM[147712];
    #define ABUF(b) (SMEM + (b) * 8192)
    #define BBUF(b) (SMEM + 16384 + (b) * 32768)
    #define HBUF    (SMEM + 81920)

    int tid = threadIdx.x, lane = tid & 63, w = tid >> 6;
    int* toks = (int*)(SMEM + 147456);
    if (tid < 64) toks[tid] = perm[beg + min(m0 + tid, cnt - 1)];
    __syncthreads();

    const short* W1e = W1 + (size_t)e * 262144;
    const short* W2e = W2 + (size_t)e * 262144;

    // ---- staging addresses (source pre-swizzled; LDS dest linear) ----
    int arow = tid >> 3, asl = tid & 7;
    int aql  = asl ^ (arow & 7);                       // logical 8-slot within 64-k pair
    const short* aS = xb + (size_t)toks[arow] * DIM + aql * 8;   // + pair*64
    int boff[4];
    #pragma unroll
    for (int i = 0; i < 4; ++i) {
        int sid = tid + i * 512, c = sid >> 2, qq = sid & 3;
        boff[i] = c * 32 + (qq ^ ((c >> 1) & 3)) * 8;  // shorts; + t*16384
    }

    // ---- fragment read constants ----
    int wr = w >> 2, wc = w & 3, lrow = lane & 15, kq = lane >> 4;
    int rA[2];
    #pragma unroll
    for (int i = 0; i < 2; ++i) rA[i] = wr * 32 + i * 16 + lrow;
    int offB[8];
    #pragma unroll
    for (int j = 0; j < 8; ++j) {
        int c = wc * 128 + j * 16 + lrow;
        offB[j] = c * 64 + ((kq ^ ((c >> 1) & 3)) << 4);
    }

    f32x4 acc[2][8];
    #pragma unroll
    for (int i = 0; i < 2; ++i)
        #pragma unroll
        for (int j = 0; j < 8; ++j) acc[i][j] = (f32x4){0.f, 0.f, 0.f, 0.f};

    // ================= L1: h = relu(xb.W1 + b1) =================
    // prologue: B0 (4), A0 (1), B1 (4) -> wait vmcnt(4) leaves B1 in flight
    {
        #pragma unroll
        for (int i_ = 0; i_ < 4; ++i_) GLOAD16(W1e + boff[i_], BBUF(0) + tid * 16 + i_ * 8192);
        GLOAD16(aS, ABUF(0) + tid * 16);
        #pragma unroll
        for (int i_ = 0; i_ < 4; ++i_) GLOAD16(W1e + 16384 + boff[i_], BBUF(1) + tid * 16 + i_ * 8192);
    }
    asm volatile("s_waitcnt vmcnt(4)" ::: "memory");   // B0 + A0 resident
    __builtin_amdgcn_s_barrier();

    #pragma unroll
    for (int t = 0; t < 16; ++t) {
        // comp(t): B from BBUF(t&1), A from ABUF((t>>1)&1) at k-half (t&1)
        {
            bf16x8 af[2], bv[8];
            #pragma unroll
            for (int j = 0; j < 8; ++j) bv[j] = *(const bf16x8*)(BBUF(t & 1) + offB[j]);
            #pragma unroll
            for (int i = 0; i < 2; ++i) {
                int sl = (((t & 1) * 4 + kq) ^ (rA[i] & 7));
                af[i] = *(const bf16x8*)(ABUF((t >> 1) & 1) + rA[i] * 128 + sl * 16);
            }
            __builtin_amdgcn_s_setprio(1);
            #pragma unroll
            for (int i = 0; i < 2; ++i)
                #pragma unroll
                for (int j = 0; j < 8; ++j)
                    acc[i][j] = __builtin_amdgcn_mfma_f32_16x16x32_bf16(af[i], bv[j], acc[i][j], 0, 0, 0);
            __builtin_amdgcn_s_setprio(0);
        }
        if (t == 15) break;
        __builtin_amdgcn_s_barrier();                  // barrier A: buf t&1 reads done
        asm volatile("" ::: "memory");
        if (t + 2 < 16) {
            #pragma unroll
            for (int i_ = 0; i_ < 4; ++i_)
                GLOAD16(W1e + (t + 2) * 16384 + boff[i_], BBUF(t & 1) + tid * 16 + i_ * 8192);
            if ((t & 1) == 0) {
                GLOAD16(aS + (t / 2 + 1) * 64, ABUF((t / 2 + 1) & 1) + tid * 16);
                asm volatile("s_waitcnt vmcnt(5)" ::: "memory");   // step t+1 data resident
            } else {
                asm volatile("s_waitcnt vmcnt(4)" ::: "memory");
            }
        } else {
            asm volatile("s_waitcnt vmcnt(0)" ::: "memory");       // drain B(15)
        }
        __builtin_amdgcn_s_barrier();                  // barrier B: buf (t+1)&1 ready
    }

    // ---- h epilogue: bias + relu -> Hb (swizzled), then reset acc ----
    {
        const float* b1e = b1 + (size_t)e * 512;
        float bv1[8];
        #pragma unroll
        for (int j = 0; j < 8; ++j) bv1[j] = b1e[wc * 128 + j * 16 + lrow];
        #pragma unroll
        for (int i = 0; i < 2; ++i)
            #pragma unroll
            for (int q = 0; q < 4; ++q) {
                int row = wr * 32 + i * 16 + kq * 4 + q;
                #pragma unroll
                for (int j = 0; j < 8; ++j) {
                    int col = wc * 128 + j * 16 + lrow;
                    float v = acc[i][j][q] + bv1[j];
                    v = v > 0.f ? v : 0.f;
                    *(short*)(HBUF + row * 1024 + (((col >> 3) ^ (row & 7)) << 4) + (col & 7) * 2) = f2bf(v);
                }
            }
    }
    __syncthreads();
    #pragma unroll
    for (int i = 0; i < 2; ++i)
        #pragma unroll
        for (int j = 0; j < 8; ++j) acc[i][j] = (f32x4){0.f, 0.f, 0.f, 0.f};

    // ================= L2: out = Hb . W2 + b2 =================
    {
        #pragma unroll
        for (int i_ = 0; i_ < 4; ++i_) GLOAD16(W2e + boff[i_], BBUF(0) + tid * 16 + i_ * 8192);
        #pragma unroll
        for (int i_ = 0; i_ < 4; ++i_) GLOAD16(W2e + 16384 + boff[i_], BBUF(1) + tid * 16 + i_ * 8192);
    }
    asm volatile("s_waitcnt vmcnt(4)" ::: "memory");
    __builtin_amdgcn_s_barrier();

    #pragma unroll
    for (int t = 0; t < 16; ++t) {
        {
            bf16x8 af[2], bv[8];
            #pragma unroll
            for (int j = 0; j < 8; ++j) bv[j] = *(const bf16x8*)(BBUF(t & 1) + offB[j]);
            #pragma unroll
            for (int i = 0; i < 2; ++i) {
                int s = (t * 4 + kq) ^ (rA[i] & 7);
                af[i] = *(const bf16x8*)(HBUF + rA[i] * 1024 + (s << 4));
            }
            __builtin_amdgcn_s_setprio(1);
            #pragma unroll
            for (int i = 0; i < 2; ++i)
                #pragma unroll
                for (int j = 0; j < 8; ++j)
                    acc[i][j] = __builtin_amdgcn_mfma_f32_16x16x32_bf16(af[i], bv[j], acc[i][j], 0, 0, 0);
            __builtin_amdgcn_s_setprio(0);
        }
        if (t == 15) break;
        __builtin_amdgcn_s_barrier();
        asm volatile("" ::: "memory");
        if (t + 2 < 16) {
            #pragma unroll
            for (int i_ = 0; i_ < 4; ++i_)
                GLOAD16(W2e + (t + 2) * 16384 + boff[i_], BBUF(t & 1) + tid * 16 + i_ * 8192);
            asm volatile("s_waitcnt vmcnt(4)" ::: "memory");
        } else {
            asm volatile("s_waitcnt vmcnt(0)" ::: "memory");
        }
        __builtin_amdgcn_s_barrier();
    }

    // ---- final epilogue: bias + f32 scatter ----
    {
        const float* b2e = b2 + (size_t)e * 512;
        float bv2[8];
        #pragma unroll
        for (int j = 0; j < 8; ++j) bv2[j] = b2e[wc * 128 + j * 16 + lrow];
        #pragma unroll
        for (int i = 0; i < 2; ++i)
            #pragma unroll
            for (int q = 0; q < 4; ++q) {
                int row = wr * 32 + i * 16 + kq * 4 + q;
                if (m0 + row < cnt) {
                    float* op = out + (size_t)toks[row] * HID;
                    #pragma unroll
                    for (int j = 0; j < 8; ++j)
                        op[wc * 128 + j * 16 + lrow] = acc[i][j][q] + bv2[j];
                }
            }
    }
    #undef ABUF
    #undef BBUF
    #undef HBUF
}

extern "C" void kernel_launch(void* const* d_in, const int* in_sizes, int n_in,
                              void* d_out, int out_size, void* d_ws, size_t ws_size,
                              hipStream_t stream)
{
    const float* x  = (const float*)d_in[0];
    const float* Wr = (const float*)d_in[1];
    const float* br = (const float*)d_in[2];
    const float* W1 = (const float*)d_in[3];
    const float* b1 = (const float*)d_in[4];
    const float* W2 = (const float*)d_in[5];
    const float* b2 = (const float*)d_in[6];

    float* out     = (float*)d_out;
    float* ids_out = out + (size_t)N_TOK * HID;

    char* ws     = (char*)d_ws;
    int* counts  = (int*)ws;            // 16 ints
    int* offsets = counts + 16;         // 11 used
    int* toff    = counts + 32;         // 11 used
    int* cursors = counts + 48;         // 16
    int* eid     = (int*)(ws + 1024);
    int* perm    = eid + N_TOK;
    short* W1b   = (short*)(ws + 1024 + (size_t)2 * N_TOK * 4);
    short* W2b   = W1b + (size_t)NEXP * 512 * 512;
    short* xb    = W2b + (size_t)NEXP * 512 * 512;

    (void)hipMemsetAsync(d_ws, 0, 1024, stream);
    router_kernel<<<2048, 256, 0, stream>>>(x, Wr, br, eid, ids_out, counts, xb);
    wconvert_kernel<<<dim3(8, 8, 2 * NEXP), 256, 0, stream>>>(W1, W2, W1b, W2b);
    offsets_kernel<<<1, 64, 0, stream>>>(counts, offsets, toff);
    scatter_kernel<<<512, 256, 0, stream>>>(eid, offsets, cursors, perm);

    int ntiles = (N_TOK + 63) / 64 + NEXP;   // upper bound on 64-row tiles (2058)
    expert_fused<<<ntiles, 512, 0, stream>>>(xb, W1b, W2b, b1, b2,
                                             offsets, toff, perm, out);
}